// Round 2
// baseline (933.807 us; speedup 1.0000x reference)
//
#include <hip/hip_runtime.h>
#include <hip/hip_cooperative_groups.h>
#include <math.h>

namespace cg = cooperative_groups;

#define C 64
#define D 16
#define EPSF 1e-8f
#define DVAR 0.5f
#define DDIST 1.5f
#define FPSCALE 65536.0f
#define INV_FPSCALE (1.0f / 65536.0f)
#define VARSCALE 4294967296.0
#define INV_VARSCALE (1.0 / 4294967296.0)
#define GRID 1024

// ws layout (32-bit words): [0,1024) g_sums (int, x2^16 fixed-point),
// [1024,1088) g_cnt (uint), [1088,1090) g_var (u64, x2^32 fixed-point; byte 4352, 8-aligned)
__global__ __launch_bounds__(256, 4) void k_fused(const float4* __restrict__ f4,
                                                  const int* __restrict__ labels, int N,
                                                  int* __restrict__ ws,
                                                  float* __restrict__ out) {
    cg::grid_group grid = cg::this_grid();
    int* g_sums = ws;                                             // 1024 ints (x2^16)
    unsigned* g_cnt = (unsigned*)(ws + 1024);                     // 64 uints
    unsigned long long* g_var = (unsigned long long*)(ws + 1088); // u64 (x2^32), 8-aligned

    __shared__ int s_sums[C * 17];
    __shared__ unsigned s_cnt[C];
    __shared__ __align__(16) float s_means[C * 20];
    __shared__ float s_w[C];
    __shared__ float s_red[256];

    int t = threadIdx.x;
    int b = blockIdx.x;
    int gid = b * 256 + t;
    int nthr = gridDim.x * 256;

    // ---- phase 0: zero workspace; init LDS histogram while waiting ----
    if (gid < 1090) ws[gid] = 0;
    for (int i = t; i < C * 17; i += 256) s_sums[i] = 0;
    if (t < C) s_cnt[t] = 0u;
    __threadfence();
    grid.sync();

    // ---- phase 1: int fixed-point LDS histogram (native ds_add, round-0-proven) ----
    // REVERSE tile order: ends on the array head so the hinge pass (forward) hits L3.
    int ntiles = (N + 255) >> 8;
    for (int it = b; it < ntiles; it += gridDim.x) {
        int tile = ntiles - 1 - it;
        int p = (tile << 8) + t;
        if (p >= N) continue;
        int c = labels[p] & (C - 1);
        float4 a  = f4[4 * p + 0];
        float4 bb = f4[4 * p + 1];
        float4 cc = f4[4 * p + 2];
        float4 dd = f4[4 * p + 3];
        int* row = &s_sums[c * 17];
        atomicAdd(row + 0,  __float2int_rn(a.x  * FPSCALE));
        atomicAdd(row + 1,  __float2int_rn(a.y  * FPSCALE));
        atomicAdd(row + 2,  __float2int_rn(a.z  * FPSCALE));
        atomicAdd(row + 3,  __float2int_rn(a.w  * FPSCALE));
        atomicAdd(row + 4,  __float2int_rn(bb.x * FPSCALE));
        atomicAdd(row + 5,  __float2int_rn(bb.y * FPSCALE));
        atomicAdd(row + 6,  __float2int_rn(bb.z * FPSCALE));
        atomicAdd(row + 7,  __float2int_rn(bb.w * FPSCALE));
        atomicAdd(row + 8,  __float2int_rn(cc.x * FPSCALE));
        atomicAdd(row + 9,  __float2int_rn(cc.y * FPSCALE));
        atomicAdd(row + 10, __float2int_rn(cc.z * FPSCALE));
        atomicAdd(row + 11, __float2int_rn(cc.w * FPSCALE));
        atomicAdd(row + 12, __float2int_rn(dd.x * FPSCALE));
        atomicAdd(row + 13, __float2int_rn(dd.y * FPSCALE));
        atomicAdd(row + 14, __float2int_rn(dd.z * FPSCALE));
        atomicAdd(row + 15, __float2int_rn(dd.w * FPSCALE));
        atomicAdd(&s_cnt[c], 1u);
    }
    __syncthreads();
    // flush with NATIVE int global atomics (fp atomicAdd w/o -munsafe-fp-atomics = CAS loop)
    for (int i = t; i < C * D; i += 256) {
        int c = i >> 4, d = i & 15;
        atomicAdd(&g_sums[i], s_sums[c * 17 + d]);
    }
    if (t < C) atomicAdd(&g_cnt[t], s_cnt[t]);
    __threadfence();
    grid.sync();

    // ---- phase 2: means from global sums; hinge pass (forward, consumes L3 head) ----
    for (int i = t; i < C * D; i += 256) {
        int c = i >> 4, d = i & 15;
        s_means[c * 20 + d] = (float)g_sums[i] * INV_FPSCALE / fmaxf((float)g_cnt[c], 1.0f);
    }
    if (t < C) s_w[t] = 1.0f / (fmaxf((float)g_cnt[t], 1.0f) * (float)C);
    __syncthreads();

    float acc = 0.0f;
    for (int p = gid; p < N; p += nthr) {
        int c = labels[p] & (C - 1);
        const float* m = &s_means[c * 20];
        float4 m0 = *(const float4*)(m + 0);
        float4 m1 = *(const float4*)(m + 4);
        float4 m2 = *(const float4*)(m + 8);
        float4 m3 = *(const float4*)(m + 12);
        float4 a  = f4[4 * p + 0];
        float4 bb = f4[4 * p + 1];
        float4 cc = f4[4 * p + 2];
        float4 dd = f4[4 * p + 3];
        float ss = 0.0f, dx;
        dx = a.x - m0.x + EPSF; ss += dx * dx;
        dx = a.y - m0.y + EPSF; ss += dx * dx;
        dx = a.z - m0.z + EPSF; ss += dx * dx;
        dx = a.w - m0.w + EPSF; ss += dx * dx;
        dx = bb.x - m1.x + EPSF; ss += dx * dx;
        dx = bb.y - m1.y + EPSF; ss += dx * dx;
        dx = bb.z - m1.z + EPSF; ss += dx * dx;
        dx = bb.w - m1.w + EPSF; ss += dx * dx;
        dx = cc.x - m2.x + EPSF; ss += dx * dx;
        dx = cc.y - m2.y + EPSF; ss += dx * dx;
        dx = cc.z - m2.z + EPSF; ss += dx * dx;
        dx = cc.w - m2.w + EPSF; ss += dx * dx;
        dx = dd.x - m3.x + EPSF; ss += dx * dx;
        dx = dd.y - m3.y + EPSF; ss += dx * dx;
        dx = dd.z - m3.z + EPSF; ss += dx * dx;
        dx = dd.w - m3.w + EPSF; ss += dx * dx;
        float h = fmaxf(sqrtf(ss) - DVAR, 0.0f);
        acc += h * h * s_w[c];
    }
    s_red[t] = acc;
    __syncthreads();
    for (int s = 128; s > 0; s >>= 1) {
        if (t < s) s_red[t] += s_red[t + s];
        __syncthreads();
    }
    // one NATIVE u64 atomic per block (partials are non-negative)
    if (t == 0) {
        unsigned long long qv = (unsigned long long)((double)s_red[0] * VARSCALE + 0.5);
        atomicAdd(g_var, qv);
    }
    __threadfence();
    grid.sync();

    // ---- phase 3: block 0 finalizes (means already in this block's s_means) ----
    if (b != 0) return;

    float var_loss = (float)((double)g_var[0] * INV_VARSCALE);

    // dist_loss over ordered pairs i != j (s_means stride 20)
    float ds = 0.0f;
    for (int p = t; p < C * C; p += 256) {
        int i = p >> 6, j = p & 63;
        if (i != j) {
            float ss = 0.0f;
            #pragma unroll
            for (int d = 0; d < D; d++) {
                float df = s_means[i * 20 + d] - s_means[j * 20 + d] + EPSF;
                ss += df * df;
            }
            float h = fmaxf(2.0f * DDIST - sqrtf(ss), 0.0f);
            ds += h * h;
        }
    }
    s_red[t] = ds;
    __syncthreads();
    for (int s = 128; s > 0; s >>= 1) {
        if (t < s) s_red[t] += s_red[t + s];
        __syncthreads();
    }
    float dist_loss = s_red[0] / (float)(C * (C - 1));
    __syncthreads();

    // reg_loss = mean_c ||m_c + EPS||
    float rg = 0.0f;
    if (t < C) {
        float ss = 0.0f;
        #pragma unroll
        for (int d = 0; d < D; d++) {
            float m = s_means[t * 20 + d] + EPSF;
            ss += m * m;
        }
        rg = sqrtf(ss);
    }
    s_red[t] = rg;
    __syncthreads();
    for (int s = 128; s > 0; s >>= 1) {
        if (t < s) s_red[t] += s_red[t + s];
        __syncthreads();
    }
    float reg_loss = s_red[0] / (float)C;

    if (t == 0) {
        out[0] = var_loss + dist_loss + 0.001f * reg_loss;
        out[1] = var_loss;
        out[2] = dist_loss;
        out[3] = reg_loss;
    }
}

extern "C" void kernel_launch(void* const* d_in, const int* in_sizes, int n_in,
                              void* d_out, int out_size, void* d_ws, size_t ws_size,
                              hipStream_t stream) {
    const float4* f4 = (const float4*)d_in[0];
    const int* labels = (const int*)d_in[1];
    int N = in_sizes[0] / D;
    int* ws = (int*)d_ws;
    float* out = (float*)d_out;

    void* args[] = {(void*)&f4, (void*)&labels, (void*)&N, (void*)&ws, (void*)&out};
    hipLaunchCooperativeKernel((const void*)k_fused, dim3(GRID), dim3(256), args, 0, stream);
}

// Round 4
// 420.040 us; speedup vs baseline: 2.2231x; 2.2231x over previous
//
#include <hip/hip_runtime.h>
#include <math.h>

#define C 64
#define D 16
#define EPSF 1e-8f
#define DVAR 0.5f
#define DDIST 1.5f
#define FPSCALE 65536.0f
#define INV_FPSCALE (1.0f / 65536.0f)
#define VARSCALE 4294967296.0
#define INV_VARSCALE (1.0 / 4294967296.0)

#define NB 2048        // blocks for the two streaming kernels (round-0 proven config)
#define SLICE 1088     // per-block private histogram: 1024 sums + 64 counts

// ws int32 layout (nothing needs pre-zeroing; everything is written before read):
//   [0 .. NB*SLICE)            per-block slices, arr[b][0..1087]
//   [GF0 .. GF0+1088)          reduced g_sums[1024] + g_cnt[64]
//   [V0 .. V0+2*NB)            per-block var partials, u64 fixed-point (V0 even -> 8B-aligned)
#define GF0 (NB * SLICE)
#define V0 (GF0 + 1088)

__global__ __launch_bounds__(256) void k_sums(const float4* __restrict__ f4,
                                              const int* __restrict__ labels, int N,
                                              int* __restrict__ arr) {
    // int fixed-point LDS histogram (native ds_add, round-0-proven body).
    // REVERSE tile order: ends on the array head so k_hinge (forward) hits L3.
    __shared__ int s_sums[C * 17];
    __shared__ unsigned s_cnt[C];
    int t = threadIdx.x;
    int b = blockIdx.x;
    for (int i = t; i < C * 17; i += 256) s_sums[i] = 0;
    if (t < C) s_cnt[t] = 0u;
    __syncthreads();

    int ntiles = (N + 255) >> 8;
    for (int it = b; it < ntiles; it += NB) {
        int tile = ntiles - 1 - it;
        int p = (tile << 8) + t;
        if (p >= N) continue;
        int c = labels[p] & (C - 1);
        float4 a  = f4[4 * p + 0];
        float4 bb = f4[4 * p + 1];
        float4 cc = f4[4 * p + 2];
        float4 dd = f4[4 * p + 3];
        int* row = &s_sums[c * 17];
        atomicAdd(row + 0,  __float2int_rn(a.x  * FPSCALE));
        atomicAdd(row + 1,  __float2int_rn(a.y  * FPSCALE));
        atomicAdd(row + 2,  __float2int_rn(a.z  * FPSCALE));
        atomicAdd(row + 3,  __float2int_rn(a.w  * FPSCALE));
        atomicAdd(row + 4,  __float2int_rn(bb.x * FPSCALE));
        atomicAdd(row + 5,  __float2int_rn(bb.y * FPSCALE));
        atomicAdd(row + 6,  __float2int_rn(bb.z * FPSCALE));
        atomicAdd(row + 7,  __float2int_rn(bb.w * FPSCALE));
        atomicAdd(row + 8,  __float2int_rn(cc.x * FPSCALE));
        atomicAdd(row + 9,  __float2int_rn(cc.y * FPSCALE));
        atomicAdd(row + 10, __float2int_rn(cc.z * FPSCALE));
        atomicAdd(row + 11, __float2int_rn(cc.w * FPSCALE));
        atomicAdd(row + 12, __float2int_rn(dd.x * FPSCALE));
        atomicAdd(row + 13, __float2int_rn(dd.y * FPSCALE));
        atomicAdd(row + 14, __float2int_rn(dd.z * FPSCALE));
        atomicAdd(row + 15, __float2int_rn(dd.w * FPSCALE));
        atomicAdd(&s_cnt[c], 1u);
    }
    __syncthreads();
    // flush: plain COALESCED stores to this block's private slice — NO global atomics
    for (int i = t; i < SLICE; i += 256) {
        int v = (i < C * D) ? s_sums[(i >> 4) * 17 + (i & 15)] : (int)s_cnt[i - C * D];
        arr[b * SLICE + i] = v;
    }
}

// Column-sum of the NB x SLICE slice matrix. int add == atomic result, bit-exact.
__global__ __launch_bounds__(256) void k_reduce(const int* __restrict__ arr,
                                                int* __restrict__ g_final) {
    __shared__ int s[256];
    int o = blockIdx.x;   // 0..1087: which histogram word
    int t = threadIdx.x;
    int part = 0;
    #pragma unroll
    for (int j = 0; j < NB / 256; j++)
        part += arr[(t + j * 256) * SLICE + o];
    s[t] = part;
    __syncthreads();
    for (int st = 128; st > 0; st >>= 1) {
        if (t < st) s[t] += s[t + st];
        __syncthreads();
    }
    if (t == 0) g_final[o] = s[0];
}

__global__ __launch_bounds__(256) void k_hinge(const float4* __restrict__ f4,
                                               const int* __restrict__ labels, int N,
                                               const int* __restrict__ g_final,
                                               unsigned long long* __restrict__ g_var) {
    // forward order to consume the L3-resident head left by k_sums (round-0 body).
    __shared__ __align__(16) float s_means[C * 20];
    __shared__ float s_w[C];
    __shared__ float s_red[256];
    int t = threadIdx.x;
    int b = blockIdx.x;
    for (int i = t; i < C * D; i += 256) {
        int c = i >> 4, d = i & 15;
        float cnt = fmaxf((float)g_final[C * D + c], 1.0f);
        s_means[c * 20 + d] = (float)g_final[i] * INV_FPSCALE / cnt;
    }
    if (t < C) s_w[t] = 1.0f / (fmaxf((float)g_final[C * D + t], 1.0f) * (float)C);
    __syncthreads();

    float acc = 0.0f;
    int gid = b * 256 + t;
    int stride = NB * 256;
    for (int p = gid; p < N; p += stride) {
        int c = labels[p] & (C - 1);
        const float* m = &s_means[c * 20];
        float4 m0 = *(const float4*)(m + 0);
        float4 m1 = *(const float4*)(m + 4);
        float4 m2 = *(const float4*)(m + 8);
        float4 m3 = *(const float4*)(m + 12);
        float4 a  = f4[4 * p + 0];
        float4 bb = f4[4 * p + 1];
        float4 cc = f4[4 * p + 2];
        float4 dd = f4[4 * p + 3];
        float ss = 0.0f, dx;
        dx = a.x - m0.x + EPSF; ss += dx * dx;
        dx = a.y - m0.y + EPSF; ss += dx * dx;
        dx = a.z - m0.z + EPSF; ss += dx * dx;
        dx = a.w - m0.w + EPSF; ss += dx * dx;
        dx = bb.x - m1.x + EPSF; ss += dx * dx;
        dx = bb.y - m1.y + EPSF; ss += dx * dx;
        dx = bb.z - m1.z + EPSF; ss += dx * dx;
        dx = bb.w - m1.w + EPSF; ss += dx * dx;
        dx = cc.x - m2.x + EPSF; ss += dx * dx;
        dx = cc.y - m2.y + EPSF; ss += dx * dx;
        dx = cc.z - m2.z + EPSF; ss += dx * dx;
        dx = cc.w - m2.w + EPSF; ss += dx * dx;
        dx = dd.x - m3.x + EPSF; ss += dx * dx;
        dx = dd.y - m3.y + EPSF; ss += dx * dx;
        dx = dd.z - m3.z + EPSF; ss += dx * dx;
        dx = dd.w - m3.w + EPSF; ss += dx * dx;
        float h = fmaxf(sqrtf(ss) - DVAR, 0.0f);
        acc += h * h * s_w[c];
    }
    s_red[t] = acc;
    __syncthreads();
    for (int s = 128; s > 0; s >>= 1) {
        if (t < s) s_red[t] += s_red[t + s];
        __syncthreads();
    }
    // plain per-block store (u64 sum is associative mod 2^64 -> bit-exact vs atomic)
    if (t == 0)
        g_var[b] = (unsigned long long)((double)s_red[0] * VARSCALE + 0.5);
}

__global__ __launch_bounds__(256) void k_final(const int* __restrict__ g_final,
                                               const unsigned long long* __restrict__ g_var,
                                               float* __restrict__ out) {
    __shared__ float s_m[C * 17];
    __shared__ float red[256];
    __shared__ unsigned long long red64[256];
    int t = threadIdx.x;
    for (int i = t; i < C * D; i += 256) {
        int c = i >> 4, d = i & 15;
        float cnt = fmaxf((float)g_final[C * D + c], 1.0f);
        s_m[c * 17 + d] = (float)g_final[i] * INV_FPSCALE / cnt;
    }
    // reduce the NB u64 var partials
    unsigned long long vq = 0ull;
    #pragma unroll
    for (int j = 0; j < NB / 256; j++) vq += g_var[t + j * 256];
    red64[t] = vq;
    __syncthreads();
    for (int s = 128; s > 0; s >>= 1) {
        if (t < s) red64[t] += red64[t + s];
        __syncthreads();
    }
    float var_loss = (float)((double)red64[0] * INV_VARSCALE);
    __syncthreads();

    // dist_loss over ordered pairs i != j
    float ds = 0.0f;
    for (int p = t; p < C * C; p += 256) {
        int i = p >> 6, j = p & 63;
        if (i != j) {
            float ss = 0.0f;
            #pragma unroll
            for (int d = 0; d < D; d++) {
                float df = s_m[i * 17 + d] - s_m[j * 17 + d] + EPSF;
                ss += df * df;
            }
            float h = fmaxf(2.0f * DDIST - sqrtf(ss), 0.0f);
            ds += h * h;
        }
    }
    red[t] = ds;
    __syncthreads();
    for (int s = 128; s > 0; s >>= 1) {
        if (t < s) red[t] += red[t + s];
        __syncthreads();
    }
    float dist_loss = red[0] / (float)(C * (C - 1));
    __syncthreads();

    // reg_loss = mean_c ||m_c + EPS||
    float rg = 0.0f;
    if (t < C) {
        float ss = 0.0f;
        #pragma unroll
        for (int d = 0; d < D; d++) {
            float m = s_m[t * 17 + d] + EPSF;
            ss += m * m;
        }
        rg = sqrtf(ss);
    }
    red[t] = rg;
    __syncthreads();
    for (int s = 128; s > 0; s >>= 1) {
        if (t < s) red[t] += red[t + s];
        __syncthreads();
    }
    float reg_loss = red[0] / (float)C;

    if (t == 0) {
        out[0] = var_loss + dist_loss + 0.001f * reg_loss;
        out[1] = var_loss;
        out[2] = dist_loss;
        out[3] = reg_loss;
    }
}

extern "C" void kernel_launch(void* const* d_in, const int* in_sizes, int n_in,
                              void* d_out, int out_size, void* d_ws, size_t ws_size,
                              hipStream_t stream) {
    const float4* f4 = (const float4*)d_in[0];
    const int* labels = (const int*)d_in[1];
    int N = in_sizes[0] / D;

    int* ws = (int*)d_ws;
    int* arr = ws;                                                // NB*1088 ints
    int* g_final = ws + GF0;                                      // 1024 sums + 64 counts
    unsigned long long* g_var = (unsigned long long*)(ws + V0);   // NB u64 partials
    float* out = (float*)d_out;

    hipLaunchKernelGGL(k_sums, dim3(NB), dim3(256), 0, stream, f4, labels, N, arr);
    hipLaunchKernelGGL(k_reduce, dim3(SLICE), dim3(256), 0, stream, arr, g_final);
    hipLaunchKernelGGL(k_hinge, dim3(NB), dim3(256), 0, stream, f4, labels, N, g_final, g_var);
    hipLaunchKernelGGL(k_final, dim3(1), dim3(256), 0, stream, g_final, g_var, out);
}